// Round 1
// baseline (272.150 us; speedup 1.0000x reference)
//
#include <hip/hip_runtime.h>
#include <math.h>

#define T_TOK 8192
#define HID   2880
#define NE    128
#define TOPK  4
#define BK    64
#define TM    32
#define WS_STRIDE 136   // padded row stride for transposed W tile (4-way write conflict, aligned b128 reads)

// ---------------------------------------------------------------------------
// Kernel 1: logits = x @ W^T + bias   (fp32, vector ALU — no fp32 MFMA on CDNA4)
// Tile: 32 tokens x 128 experts per 256-thread block, BK=64.
// Per thread: 4 tokens x 4 experts register tile, dual accumulation chains
// (halves sequential-sum rounding error to stay consistent with numpy ref).
// ---------------------------------------------------------------------------
__global__ __launch_bounds__(256) void logits_gemm(const float* __restrict__ x,
                                                   const float* __restrict__ w,
                                                   const float* __restrict__ bias,
                                                   float* __restrict__ logits) {
  __shared__ float xs[TM][BK];          // natural [token][k] — scalar broadcast reads
  __shared__ float ws[BK][WS_STRIDE];   // transposed [k][expert], padded

  const int t  = threadIdx.x;
  const int m0 = blockIdx.x * TM;
  const int ty = t >> 5;   // 0..7  -> tokens  ty*4 .. ty*4+3
  const int tx = t & 31;   // 0..31 -> experts tx*4 .. tx*4+3

  float acc0[4][4] = {};
  float acc1[4][4] = {};

  for (int k0 = 0; k0 < HID; k0 += BK) {
    // stage x tile: 32 tokens x 64 k = 512 float4 (2 per thread), coalesced
#pragma unroll
    for (int j = 0; j < 2; ++j) {
      const int idx = j * 256 + t;      // 0..511
      const int m   = idx >> 4;         // 0..31
      const int kq  = idx & 15;         // 0..15
      const float4 v = *(const float4*)(x + (size_t)(m0 + m) * HID + k0 + kq * 4);
      *(float4*)(&xs[m][kq * 4]) = v;   // contiguous LDS write, conflict-free
    }
    // stage W tile transposed: 128 experts x 64 k = 2048 float4 (8 per thread)
#pragma unroll
    for (int j = 0; j < 8; ++j) {
      const int idx = j * 256 + t;      // 0..2047
      const int n   = idx >> 4;         // 0..127
      const int kq  = idx & 15;         // 0..15
      const float4 v = *(const float4*)(w + (size_t)n * HID + k0 + kq * 4);
      ws[kq * 4 + 0][n] = v.x;
      ws[kq * 4 + 1][n] = v.y;
      ws[kq * 4 + 2][n] = v.z;
      ws[kq * 4 + 3][n] = v.w;
    }
    __syncthreads();

#pragma unroll
    for (int kk = 0; kk < BK; kk += 2) {
      float xv0[4], xv1[4];
#pragma unroll
      for (int i = 0; i < 4; ++i) {
        xv0[i] = xs[ty * 4 + i][kk];
        xv1[i] = xs[ty * 4 + i][kk + 1];
      }
      const float4 wv0 = *(const float4*)(&ws[kk][tx * 4]);
      const float4 wv1 = *(const float4*)(&ws[kk + 1][tx * 4]);
#pragma unroll
      for (int i = 0; i < 4; ++i) {
        acc0[i][0] = fmaf(xv0[i], wv0.x, acc0[i][0]);
        acc0[i][1] = fmaf(xv0[i], wv0.y, acc0[i][1]);
        acc0[i][2] = fmaf(xv0[i], wv0.z, acc0[i][2]);
        acc0[i][3] = fmaf(xv0[i], wv0.w, acc0[i][3]);
        acc1[i][0] = fmaf(xv1[i], wv1.x, acc1[i][0]);
        acc1[i][1] = fmaf(xv1[i], wv1.y, acc1[i][1]);
        acc1[i][2] = fmaf(xv1[i], wv1.z, acc1[i][2]);
        acc1[i][3] = fmaf(xv1[i], wv1.w, acc1[i][3]);
      }
    }
    __syncthreads();
  }

  const int n0 = tx * 4;
  const float4 bv = *(const float4*)(bias + n0);
#pragma unroll
  for (int i = 0; i < 4; ++i) {
    float4 o;
    o.x = acc0[i][0] + acc1[i][0] + bv.x;
    o.y = acc0[i][1] + acc1[i][1] + bv.y;
    o.z = acc0[i][2] + acc1[i][2] + bv.z;
    o.w = acc0[i][3] + acc1[i][3] + bv.w;
    *(float4*)(logits + (size_t)(m0 + ty * 4 + i) * NE + n0) = o;
  }
}

// ---------------------------------------------------------------------------
// Kernel 2: per-token top-4 (desc, lower-index tie-break like jax.lax.top_k),
// softmax over top-4, histogram via float atomicAdd (integer counts -> exact,
// order-independent -> deterministic).
// One wave per token; 4 waves per block.
// Out layout: [0, T*4) scores | [T*4, 2*T*4) indices-as-float | [2*T*4, +128) counts
// ---------------------------------------------------------------------------
__global__ __launch_bounds__(256) void topk_kernel(const float* __restrict__ logits,
                                                   float* __restrict__ out) {
  const int lane = threadIdx.x & 63;
  const int wave = threadIdx.x >> 6;
  const int tok  = blockIdx.x * 4 + wave;

  const float* lrow = logits + (size_t)tok * NE;
  float v0 = lrow[lane];
  float v1 = lrow[lane + 64];
  const int i0 = lane, i1 = lane + 64;

  float topv[TOPK];
  int   topi[TOPK];

#pragma unroll
  for (int r = 0; r < TOPK; ++r) {
    float bv; int bi;
    if (v0 >= v1) { bv = v0; bi = i0; }   // i0 < i1, so >= implements the tie-break
    else          { bv = v1; bi = i1; }
#pragma unroll
    for (int off = 32; off > 0; off >>= 1) {
      const float ov = __shfl_xor(bv, off);
      const int   oi = __shfl_xor(bi, off);
      if (ov > bv || (ov == bv && oi < bi)) { bv = ov; bi = oi; }
    }
    topv[r] = bv; topi[r] = bi;
    if (bi == i0) v0 = -INFINITY;
    if (bi == i1) v1 = -INFINITY;
  }

  const float m = topv[0];
  float s = 0.f;
#pragma unroll
  for (int r = 0; r < TOPK; ++r) s += expf(topv[r] - m);

  if (lane < TOPK) {
    out[(size_t)tok * TOPK + lane] = expf(topv[lane] - m) / s;
    out[(size_t)T_TOK * TOPK + (size_t)tok * TOPK + lane] = (float)topi[lane];
    atomicAdd(out + 2 * (size_t)T_TOK * TOPK + topi[lane], 1.0f);
  }
}

extern "C" void kernel_launch(void* const* d_in, const int* in_sizes, int n_in,
                              void* d_out, int out_size, void* d_ws, size_t ws_size,
                              hipStream_t stream) {
  const float* x    = (const float*)d_in[0];
  const float* w    = (const float*)d_in[1];
  const float* bias = (const float*)d_in[2];
  float* out    = (float*)d_out;
  float* logits = (float*)d_ws;   // 8192*128*4 = 4 MB scratch

  logits_gemm<<<T_TOK / TM, 256, 0, stream>>>(x, w, bias, logits);

  // zero the histogram region (d_out is NOT re-poisoned between replays)
  hipMemsetAsync(out + 2 * (size_t)T_TOK * TOPK, 0, NE * sizeof(float), stream);

  topk_kernel<<<T_TOK / 4, 256, 0, stream>>>(logits, out);
}

// Round 2
// 186.444 us; speedup vs baseline: 1.4597x; 1.4597x over previous
//
#include <hip/hip_runtime.h>
#include <math.h>

#define T_TOK 8192
#define HID   2880
#define NE    128
#define TOPK  4
#define BK    32
#define TM    32
#define NSTEPS (HID / BK)   // 90
#define WS_STRIDE 132       // ≡4 (mod 8): 16B-aligned rows, transpose-writes 4-way (not 16-way)

// ---------------------------------------------------------------------------
// Kernel 1: partial logits = x @ W^T over a K-chunk (fp32 vector ALU; no fp32
// MFMA on CDNA4). Tile: 32 tokens x 128 experts, BK=32, 256 threads,
// 4x4 register tile/thread with dual accumulation chains.
// Split-K: blockIdx.x % split selects the K-chunk; partials land in d_ws.
// Bias is NOT added here (added in the reduce+topk kernel).
// ---------------------------------------------------------------------------
__global__ __launch_bounds__(256) void logits_gemm(const float* __restrict__ x,
                                                   const float* __restrict__ w,
                                                   float* __restrict__ part,
                                                   int split) {
  __shared__ float xs[TM][BK];          // [token][k] — scalar broadcast reads
  __shared__ float ws[BK][WS_STRIDE];   // transposed [k][expert]

  const int t    = threadIdx.x;
  const int s    = blockIdx.x % split;  // K-chunk id
  const int tile = blockIdx.x / split;  // token-tile id
  const int m0   = tile * TM;
  const int ty   = t >> 5;   // 0..7  -> tokens  ty*4 .. ty*4+3
  const int tx   = t & 31;   // 0..31 -> experts tx*4 .. tx*4+3

  const int base  = NSTEPS / split, rem = NSTEPS % split;
  const int cnt   = base + (s < rem ? 1 : 0);
  const int start = s * base + (s < rem ? s : rem);

  float acc0[4][4] = {};
  float acc1[4][4] = {};

  for (int st = 0; st < cnt; ++st) {
    const int k0 = (start + st) * BK;

    // stage x tile: 32 tokens x 32 k = 256 float4, 1/thread, fully coalesced,
    // LDS write address = t*16 B -> conflict-free
    {
      const int m  = t >> 3;
      const int kq = t & 7;
      *(float4*)(&xs[m][kq * 4]) =
          *(const float4*)(x + (size_t)(m0 + m) * HID + k0 + kq * 4);
    }
    // stage W tile transposed: 128 experts x 32 k = 1024 float4, 4/thread
#pragma unroll
    for (int j = 0; j < 4; ++j) {
      const int idx = j * 256 + t;
      const int n   = idx >> 3;   // expert
      const int kq  = idx & 7;    // k-quad
      const float4 v = *(const float4*)(w + (size_t)n * HID + k0 + kq * 4);
      ws[kq * 4 + 0][n] = v.x;
      ws[kq * 4 + 1][n] = v.y;
      ws[kq * 4 + 2][n] = v.z;
      ws[kq * 4 + 3][n] = v.w;
    }
    __syncthreads();

#pragma unroll
    for (int kk = 0; kk < BK; kk += 2) {
      float2 xv[4];
#pragma unroll
      for (int i = 0; i < 4; ++i)
        xv[i] = *(const float2*)(&xs[ty * 4 + i][kk]);   // ds_read_b64, broadcast
      const float4 wv0 = *(const float4*)(&ws[kk][tx * 4]);      // b128, conflict-free
      const float4 wv1 = *(const float4*)(&ws[kk + 1][tx * 4]);
#pragma unroll
      for (int i = 0; i < 4; ++i) {
        acc0[i][0] = fmaf(xv[i].x, wv0.x, acc0[i][0]);
        acc0[i][1] = fmaf(xv[i].x, wv0.y, acc0[i][1]);
        acc0[i][2] = fmaf(xv[i].x, wv0.z, acc0[i][2]);
        acc0[i][3] = fmaf(xv[i].x, wv0.w, acc0[i][3]);
        acc1[i][0] = fmaf(xv[i].y, wv1.x, acc1[i][0]);
        acc1[i][1] = fmaf(xv[i].y, wv1.y, acc1[i][1]);
        acc1[i][2] = fmaf(xv[i].y, wv1.z, acc1[i][2]);
        acc1[i][3] = fmaf(xv[i].y, wv1.w, acc1[i][3]);
      }
    }
    __syncthreads();
  }

  const int n0 = tx * 4;
  float* prow = part + (size_t)s * T_TOK * NE;
#pragma unroll
  for (int i = 0; i < 4; ++i) {
    float4 o;
    o.x = acc0[i][0] + acc1[i][0];
    o.y = acc0[i][1] + acc1[i][1];
    o.z = acc0[i][2] + acc1[i][2];
    o.w = acc0[i][3] + acc1[i][3];
    *(float4*)(prow + (size_t)(m0 + ty * 4 + i) * NE + n0) = o;
  }
}

// ---------------------------------------------------------------------------
// Kernel 2: reduce split-K partials (fixed order -> deterministic) + bias,
// then per-token top-4 (desc, lower-index tie-break), softmax over top-4,
// histogram via fp32 atomicAdd of 1.0 (integer counts -> exact & order-free).
// One wave per token.
// ---------------------------------------------------------------------------
__global__ __launch_bounds__(256) void topk_kernel(const float* __restrict__ part,
                                                   const float* __restrict__ bias,
                                                   float* __restrict__ out,
                                                   int split) {
  const int lane = threadIdx.x & 63;
  const int wave = threadIdx.x >> 6;
  const int tok  = blockIdx.x * 4 + wave;

  float v0 = 0.f, v1 = 0.f;
  for (int s = 0; s < split; ++s) {   // fixed k-order summation
    const float* prow = part + (size_t)s * T_TOK * NE + (size_t)tok * NE;
    v0 += prow[lane];
    v1 += prow[lane + 64];
  }
  v0 += bias[lane];
  v1 += bias[lane + 64];
  const int i0 = lane, i1 = lane + 64;

  float topv[TOPK];
  int   topi[TOPK];

#pragma unroll
  for (int r = 0; r < TOPK; ++r) {
    float bv; int bi;
    if (v0 >= v1) { bv = v0; bi = i0; }   // i0 < i1 implements lower-index tie-break
    else          { bv = v1; bi = i1; }
#pragma unroll
    for (int off = 32; off > 0; off >>= 1) {
      const float ov = __shfl_xor(bv, off);
      const int   oi = __shfl_xor(bi, off);
      if (ov > bv || (ov == bv && oi < bi)) { bv = ov; bi = oi; }
    }
    topv[r] = bv; topi[r] = bi;
    if (bi == i0) v0 = -INFINITY;
    if (bi == i1) v1 = -INFINITY;
  }

  const float m = topv[0];
  float s = 0.f;
#pragma unroll
  for (int r = 0; r < TOPK; ++r) s += expf(topv[r] - m);

  if (lane < TOPK) {
    out[(size_t)tok * TOPK + lane] = expf(topv[lane] - m) / s;
    out[(size_t)T_TOK * TOPK + (size_t)tok * TOPK + lane] = (float)topi[lane];
    atomicAdd(out + 2 * (size_t)T_TOK * TOPK + topi[lane], 1.0f);
  }
}

extern "C" void kernel_launch(void* const* d_in, const int* in_sizes, int n_in,
                              void* d_out, int out_size, void* d_ws, size_t ws_size,
                              hipStream_t stream) {
  const float* x    = (const float*)d_in[0];
  const float* w    = (const float*)d_in[1];
  const float* bias = (const float*)d_in[2];
  float* out  = (float*)d_out;
  float* part = (float*)d_ws;

  // split-K factor: 4 if the workspace can hold 4 partial logit planes (16 MB)
  const size_t plane = (size_t)T_TOK * NE * sizeof(float);   // 4 MB
  const int split = (ws_size >= 4 * plane) ? 4 : 1;

  logits_gemm<<<(T_TOK / TM) * split, 256, 0, stream>>>(x, w, part, split);

  // zero the histogram region (d_out is NOT re-poisoned between replays)
  hipMemsetAsync(out + 2 * (size_t)T_TOK * TOPK, 0, NE * sizeof(float), stream);

  topk_kernel<<<T_TOK / 4, 256, 0, stream>>>(part, bias, out, split);
}

// Round 3
// 116.426 us; speedup vs baseline: 2.3375x; 1.6014x over previous
//
#include <hip/hip_runtime.h>
#include <math.h>

#define T_TOK 8192
#define HID   2880
#define NE    128
#define TOPK  4
#define BK    32
#define TM    128
#define NSTEPS (HID / BK)    // 90
#define LDS_STRIDE 140       // 128 data cols + 4-float pad inserted every 32 cols

// column map: insert a 4-float gap after every 32 floats -> per-16-lane-phase
// conflict-free b128 reads (chunk starts hit each bank-group at most once)
__device__ __forceinline__ int cmap(int c) { return c + ((c >> 5) << 2); }

// ---------------------------------------------------------------------------
// Kernel 1: partial logits = x @ W^T over a K-chunk. fp32 vector ALU (no fp32
// MFMA on CDNA4). Tile: 128 tokens x 128 experts, 256 threads, 8x8 per thread
// -> 1.0 FMA/LDS-byte (LDS pipe at ~50%, FMA-bound). Split-K across blocks,
// partial planes in d_ws, reduced deterministically in kernel 2.
// Global->reg prefetch of step st+1 overlaps the FMA loop of step st.
// ---------------------------------------------------------------------------
__global__ __launch_bounds__(256) void logits_gemm(const float* __restrict__ x,
                                                   const float* __restrict__ w,
                                                   float* __restrict__ part,
                                                   int split) {
  __shared__ float xs[BK][LDS_STRIDE];   // [k][token]  (transposed, padded)
  __shared__ float ws[BK][LDS_STRIDE];   // [k][expert] (transposed, padded)

  const int t    = threadIdx.x;
  const int s    = blockIdx.x % split;   // K-chunk id
  const int tile = blockIdx.x / split;   // token-tile id
  const int m0   = tile * TM;

  // bit-interleaved 16x16 thread grid: per 16-lane phase -> 4 distinct tx,
  // 4 distinct ty -> both LDS read streams conflict-free (see cmap analysis)
  const int tx = (t & 3) | (((t >> 4) & 3) << 2);   // expert group: 8 experts
  const int ty = ((t >> 2) & 3) | (((t >> 6) & 3) << 2); // token group: 8 tokens

  const int base  = NSTEPS / split, rem = NSTEPS % split;
  const int cnt   = base + (s < rem ? 1 : 0);
  const int start = s * base + (s < rem ? s : rem);

  const int sm  = t >> 3;   // staging row within 32-group
  const int skq = t & 7;    // staging k-quad

  float acc[8][8] = {{0.f}};
  float4 rx[4], rw[4];

  // prologue: load step 0 into regs
  {
    const int k0 = start * BK;
#pragma unroll
    for (int j = 0; j < 4; ++j) {
      const int r = j * 32 + sm;
      rx[j] = *(const float4*)(x + (size_t)(m0 + r) * HID + k0 + skq * 4);
      rw[j] = *(const float4*)(w + (size_t)r * HID + k0 + skq * 4);
    }
  }

  const int xc = cmap(ty * 8);
  const int wc = cmap(tx * 8);

  for (int st = 0; st < cnt; ++st) {
    // regs -> LDS (transposed scalar writes; ~4-way, amortized: 32 writes vs
    // 128 b128 reads per thread-step)
#pragma unroll
    for (int j = 0; j < 4; ++j) {
      const int cr = cmap(j * 32 + sm);
      xs[skq * 4 + 0][cr] = rx[j].x;
      xs[skq * 4 + 1][cr] = rx[j].y;
      xs[skq * 4 + 2][cr] = rx[j].z;
      xs[skq * 4 + 3][cr] = rx[j].w;
      ws[skq * 4 + 0][cr] = rw[j].x;
      ws[skq * 4 + 1][cr] = rw[j].y;
      ws[skq * 4 + 2][cr] = rw[j].z;
      ws[skq * 4 + 3][cr] = rw[j].w;
    }
    __syncthreads();

    // prefetch next step's global tiles (latency hides under the FMA loop)
    if (st + 1 < cnt) {
      const int k0 = (start + st + 1) * BK;
#pragma unroll
      for (int j = 0; j < 4; ++j) {
        const int r = j * 32 + sm;
        rx[j] = *(const float4*)(x + (size_t)(m0 + r) * HID + k0 + skq * 4);
        rw[j] = *(const float4*)(w + (size_t)r * HID + k0 + skq * 4);
      }
    }

#pragma unroll 8
    for (int kk = 0; kk < BK; ++kk) {
      float xv[8], wv[8];
      *(float4*)&xv[0] = *(const float4*)(&xs[kk][xc]);
      *(float4*)&xv[4] = *(const float4*)(&xs[kk][xc + 4]);
      *(float4*)&wv[0] = *(const float4*)(&ws[kk][wc]);
      *(float4*)&wv[4] = *(const float4*)(&ws[kk][wc + 4]);
#pragma unroll
      for (int i = 0; i < 8; ++i)
#pragma unroll
        for (int jj = 0; jj < 8; ++jj)
          acc[i][jj] = fmaf(xv[i], wv[jj], acc[i][jj]);
    }
    __syncthreads();
  }

  float* prow = part + (size_t)s * T_TOK * NE + (size_t)(m0 + ty * 8) * NE + tx * 8;
#pragma unroll
  for (int i = 0; i < 8; ++i) {
    *(float4*)(prow + (size_t)i * NE)
        = make_float4(acc[i][0], acc[i][1], acc[i][2], acc[i][3]);
    *(float4*)(prow + (size_t)i * NE + 4)
        = make_float4(acc[i][4], acc[i][5], acc[i][6], acc[i][7]);
  }
}

// ---------------------------------------------------------------------------
// Kernel 2: reduce split-K partials in fixed order + bias, per-token top-4
// (desc, lower-index tie-break = jax.lax.top_k), softmax over the 4.
// One wave per token. No atomics (counts done by kernel 3).
// Out layout: [0,T*4) scores | [T*4,2*T*4) indices-as-float | [2*T*4,+128) counts
// ---------------------------------------------------------------------------
__global__ __launch_bounds__(256) void topk_kernel(const float* __restrict__ part,
                                                   const float* __restrict__ bias,
                                                   float* __restrict__ out,
                                                   int split) {
  const int lane = threadIdx.x & 63;
  const int wave = threadIdx.x >> 6;
  const int tok  = blockIdx.x * 4 + wave;

  float v0 = 0.f, v1 = 0.f;
  for (int s = 0; s < split; ++s) {   // fixed order -> deterministic
    const float* prow = part + (size_t)s * T_TOK * NE + (size_t)tok * NE;
    v0 += prow[lane];
    v1 += prow[lane + 64];
  }
  v0 += bias[lane];
  v1 += bias[lane + 64];
  const int i0 = lane, i1 = lane + 64;

  float topv[TOPK];
  int   topi[TOPK];

#pragma unroll
  for (int r = 0; r < TOPK; ++r) {
    float bv; int bi;
    if (v0 >= v1) { bv = v0; bi = i0; }   // i0 < i1 implements lower-index tie-break
    else          { bv = v1; bi = i1; }
#pragma unroll
    for (int off = 32; off > 0; off >>= 1) {
      const float ov = __shfl_xor(bv, off);
      const int   oi = __shfl_xor(bi, off);
      if (ov > bv || (ov == bv && oi < bi)) { bv = ov; bi = oi; }
    }
    topv[r] = bv; topi[r] = bi;
    if (bi == i0) v0 = -INFINITY;
    if (bi == i1) v1 = -INFINITY;
  }

  const float m = topv[0];
  float sum = 0.f;
#pragma unroll
  for (int r = 0; r < TOPK; ++r) sum += expf(topv[r] - m);

  if (lane < TOPK) {
    out[(size_t)tok * TOPK + lane] = expf(topv[lane] - m) / sum;
    out[(size_t)T_TOK * TOPK + (size_t)tok * TOPK + lane] = (float)topi[lane];
  }
}

// ---------------------------------------------------------------------------
// Kernel 3: expert histogram, atomic-free and deterministic. One block per
// expert scans the 32768 index floats (16 MB total reads, L2/HBM ~3 us).
// ---------------------------------------------------------------------------
__global__ __launch_bounds__(256) void count_kernel(const float* __restrict__ idxf,
                                                    float* __restrict__ counts) {
  const int e = blockIdx.x;
  const int t = threadIdx.x;
  const float ef = (float)e;
  int c = 0;
  for (int i = t; i < T_TOK * TOPK; i += 256)
    c += (idxf[i] == ef) ? 1 : 0;
#pragma unroll
  for (int off = 32; off > 0; off >>= 1) c += __shfl_xor(c, off);
  __shared__ int sh[4];
  if ((t & 63) == 0) sh[t >> 6] = c;
  __syncthreads();
  if (t == 0) counts[e] = (float)(sh[0] + sh[1] + sh[2] + sh[3]);
}

extern "C" void kernel_launch(void* const* d_in, const int* in_sizes, int n_in,
                              void* d_out, int out_size, void* d_ws, size_t ws_size,
                              hipStream_t stream) {
  const float* x    = (const float*)d_in[0];
  const float* w    = (const float*)d_in[1];
  const float* bias = (const float*)d_in[2];
  float* out  = (float*)d_out;
  float* part = (float*)d_ws;

  const size_t plane = (size_t)T_TOK * NE * sizeof(float);   // 4 MB per plane
  int split = 1;
  if      (ws_size >= 8 * plane) split = 8;   // 512 blocks = 2/CU
  else if (ws_size >= 4 * plane) split = 4;
  else if (ws_size >= 2 * plane) split = 2;

  logits_gemm<<<(T_TOK / TM) * split, 256, 0, stream>>>(x, w, part, split);
  topk_kernel<<<T_TOK / 4, 256, 0, stream>>>(part, bias, out, split);
  count_kernel<<<NE, 256, 0, stream>>>(out + (size_t)T_TOK * TOPK,
                                       out + 2 * (size_t)T_TOK * TOPK);
}

// Round 4
// 65.588 us; speedup vs baseline: 4.1494x; 1.7751x over previous
//
#include <hip/hip_runtime.h>
#include <math.h>

#define T_TOK 8192
#define HID   2880
#define NE    128
#define TOPK  4
#define NKS   (HID / 32)     // 90 K-steps of 32
#define LROW  40             // LDS row stride in halves (80 B = 5 chunks -> conflict-free b128)

typedef _Float16 f16x8 __attribute__((ext_vector_type(8)));
typedef float    f32x4 __attribute__((ext_vector_type(4)));

// ---------------------------------------------------------------------------
// Kernel 0: convert W (fp32) -> fragment-linear fp16 hi/lo planes, scaled x32
// (keeps lo-part out of fp16 denormal range; 2^-5 folded into GEMM epilogue).
// Layout: fragment (k-step gs, expert-group j, plane p) = 1024 contiguous bytes
// at ((gs*8+j)*2+p)*1024; within, lane l = (k-octet<<4)|(n&15) holds 8
// k-consecutive halves -> exactly the mfma_16x16x32 B-operand per-lane chunk.
// ---------------------------------------------------------------------------
__global__ __launch_bounds__(256) void convert_w(const float* __restrict__ w,
                                                 _Float16* __restrict__ wc) {
  const int c = blockIdx.x * 256 + threadIdx.x;   // one 8-k chunk of one expert
  if (c >= NE * (HID / 8)) return;
  const int n  = c / (HID / 8);
  const int k8 = c % (HID / 8);
  const float4 v0 = *(const float4*)(w + (size_t)n * HID + k8 * 8);
  const float4 v1 = *(const float4*)(w + (size_t)n * HID + k8 * 8 + 4);
  const float f[8] = {v0.x, v0.y, v0.z, v0.w, v1.x, v1.y, v1.z, v1.w};
  f16x8 h, l;
#pragma unroll
  for (int i = 0; i < 8; ++i) {
    const float s = f[i] * 32.0f;
    const _Float16 hi = (_Float16)s;
    h[i] = hi;
    l[i] = (_Float16)(s - (float)hi);
  }
  const int gs   = k8 >> 2;
  const int oct  = k8 & 3;
  const int j    = n >> 4;
  const int lane = (oct << 4) | (n & 15);
  _Float16* base = wc + ((size_t)(gs * 8 + j) * 2) * 512 + lane * 8;
  *(f16x8*)(base)       = h;    // plane 0 (hi)
  *(f16x8*)(base + 512) = l;    // plane 1 (lo)
}

// ---------------------------------------------------------------------------
// Kernel 1: partial logits via fp16x2 MFMA emulation of fp32.
// acc += xh*wh + xl*wh + xh*wl  (3x mfma_f32_16x16x32_f16), result * 2^-5.
// Tile 128 tok x 128 exp, 4 waves (2x2), 4x4 frags/wave. A staged in LDS
// (converted fp32->f16x2 in-kernel, padded rows), B fragments straight from
// the pre-arranged global planes (1.5 MB, L2-hot). Split-K partial planes.
// ---------------------------------------------------------------------------
__global__ __launch_bounds__(256, 2) void logits_mfma(const float* __restrict__ x,
                                                      const _Float16* __restrict__ wc,
                                                      float* __restrict__ part,
                                                      int split) {
  __shared__ _Float16 xh[128 * LROW];
  __shared__ _Float16 xl[128 * LROW];

  const int t    = threadIdx.x;
  const int s    = blockIdx.x % split;
  const int tile = blockIdx.x / split;
  const int m0   = tile * 128;

  const int lane = t & 63;
  const int wv   = t >> 6;
  const int wm   = wv >> 1;   // token half (0..1)
  const int wn   = wv & 1;    // expert half (0..1)

  const int kbase = NKS / split, krem = NKS % split;
  const int cnt   = kbase + (s < krem ? 1 : 0);
  const int st0   = s * kbase + (s < krem ? s : krem);

  const int srow = t >> 1;    // staging row 0..127
  const int skh  = t & 1;     // k-half (16 els)

  f32x4 acc[4][4] = {};

  float4 xr[4];
  {
    const float* xp = x + (size_t)(m0 + srow) * HID + st0 * 32 + skh * 16;
#pragma unroll
    for (int q = 0; q < 4; ++q) xr[q] = *(const float4*)(xp + q * 4);
  }

  for (int st = 0; st < cnt; ++st) {
    const int gs = st0 + st;

    // B fragments for this step (global, L2-hot)
    f16x8 bh[4], bl[4];
    const _Float16* bp = wc + ((size_t)gs * 8 + wn * 4) * 2 * 512 + lane * 8;
#pragma unroll
    for (int nj = 0; nj < 4; ++nj) {
      bh[nj] = *(const f16x8*)(bp + (size_t)nj * 1024);
      bl[nj] = *(const f16x8*)(bp + (size_t)nj * 1024 + 512);
    }

    __syncthreads();   // previous step's LDS readers done

    // convert current x chunk -> fp16 hi/lo, stage to LDS (padded rows)
    {
      union { float4 v[4]; float f[16]; } u;
      u.v[0] = xr[0]; u.v[1] = xr[1]; u.v[2] = xr[2]; u.v[3] = xr[3];
      f16x8 h0, h1, l0, l1;
#pragma unroll
      for (int i = 0; i < 8; ++i) {
        const float a = u.f[i];
        const _Float16 ha = (_Float16)a;
        h0[i] = ha; l0[i] = (_Float16)(a - (float)ha);
        const float b = u.f[i + 8];
        const _Float16 hb = (_Float16)b;
        h1[i] = hb; l1[i] = (_Float16)(b - (float)hb);
      }
      const int off = srow * LROW + skh * 16;
      *(f16x8*)&xh[off]     = h0;
      *(f16x8*)&xh[off + 8] = h1;
      *(f16x8*)&xl[off]     = l0;
      *(f16x8*)&xl[off + 8] = l1;
    }
    __syncthreads();

    // prefetch next step's x (hides HBM latency under MFMA loop)
    if (st + 1 < cnt) {
      const float* xp = x + (size_t)(m0 + srow) * HID + (gs + 1) * 32 + skh * 16;
#pragma unroll
      for (int q = 0; q < 4; ++q) xr[q] = *(const float4*)(xp + q * 4);
    }

    // 48 MFMAs: 3 products per (mi,nj)
#pragma unroll
    for (int mi = 0; mi < 4; ++mi) {
      const int off = (wm * 64 + mi * 16 + (lane & 15)) * LROW + (lane >> 4) * 8;
      const f16x8 ah = *(const f16x8*)&xh[off];
      const f16x8 al = *(const f16x8*)&xl[off];
#pragma unroll
      for (int nj = 0; nj < 4; ++nj) {
        acc[mi][nj] = __builtin_amdgcn_mfma_f32_16x16x32_f16(ah, bh[nj], acc[mi][nj], 0, 0, 0);
        acc[mi][nj] = __builtin_amdgcn_mfma_f32_16x16x32_f16(al, bh[nj], acc[mi][nj], 0, 0, 0);
        acc[mi][nj] = __builtin_amdgcn_mfma_f32_16x16x32_f16(ah, bl[nj], acc[mi][nj], 0, 0, 0);
      }
    }
  }

  // epilogue: C/D layout col=lane&15 (expert), row=(lane>>4)*4+reg (token)
  float* pl = part + (size_t)s * T_TOK * NE;
  const int r0 = m0 + wm * 64 + (lane >> 4) * 4;
  const int e0 = wn * 64 + (lane & 15);
#pragma unroll
  for (int mi = 0; mi < 4; ++mi)
#pragma unroll
    for (int nj = 0; nj < 4; ++nj) {
      float* pp = pl + (size_t)(r0 + mi * 16) * NE + e0 + nj * 16;
#pragma unroll
      for (int r = 0; r < 4; ++r) pp[(size_t)r * NE] = acc[mi][nj][r] * 0.03125f;
    }
}

// ---------------------------------------------------------------------------
// Kernel 2: reduce split-K partials in fixed order + bias, per-token top-4
// (desc, lower-index tie-break = jax.lax.top_k), softmax over the 4.
// ---------------------------------------------------------------------------
__global__ __launch_bounds__(256) void topk_kernel(const float* __restrict__ part,
                                                   const float* __restrict__ bias,
                                                   float* __restrict__ out,
                                                   int split) {
  const int lane = threadIdx.x & 63;
  const int wave = threadIdx.x >> 6;
  const int tok  = blockIdx.x * 4 + wave;

  float v0 = 0.f, v1 = 0.f;
  for (int s = 0; s < split; ++s) {
    const float* prow = part + (size_t)s * T_TOK * NE + (size_t)tok * NE;
    v0 += prow[lane];
    v1 += prow[lane + 64];
  }
  v0 += bias[lane];
  v1 += bias[lane + 64];
  const int i0 = lane, i1 = lane + 64;

  float topv[TOPK];
  int   topi[TOPK];

#pragma unroll
  for (int r = 0; r < TOPK; ++r) {
    float bv; int bi;
    if (v0 >= v1) { bv = v0; bi = i0; }
    else          { bv = v1; bi = i1; }
#pragma unroll
    for (int off = 32; off > 0; off >>= 1) {
      const float ov = __shfl_xor(bv, off);
      const int   oi = __shfl_xor(bi, off);
      if (ov > bv || (ov == bv && oi < bi)) { bv = ov; bi = oi; }
    }
    topv[r] = bv; topi[r] = bi;
    if (bi == i0) v0 = -INFINITY;
    if (bi == i1) v1 = -INFINITY;
  }

  const float m = topv[0];
  float sum = 0.f;
#pragma unroll
  for (int r = 0; r < TOPK; ++r) sum += expf(topv[r] - m);

  if (lane < TOPK) {
    out[(size_t)tok * TOPK + lane] = expf(topv[lane] - m) / sum;
    out[(size_t)T_TOK * TOPK + (size_t)tok * TOPK + lane] = (float)topi[lane];
  }
}

// ---------------------------------------------------------------------------
// Kernel 3: expert histogram, atomic-free & deterministic.
// ---------------------------------------------------------------------------
__global__ __launch_bounds__(256) void count_kernel(const float* __restrict__ idxf,
                                                    float* __restrict__ counts) {
  const int e = blockIdx.x;
  const int t = threadIdx.x;
  const float ef = (float)e;
  int c = 0;
  for (int i = t; i < T_TOK * TOPK; i += 256)
    c += (idxf[i] == ef) ? 1 : 0;
#pragma unroll
  for (int off = 32; off > 0; off >>= 1) c += __shfl_xor(c, off);
  __shared__ int sh[4];
  if ((t & 63) == 0) sh[t >> 6] = c;
  __syncthreads();
  if (t == 0) counts[e] = (float)(sh[0] + sh[1] + sh[2] + sh[3]);
}

extern "C" void kernel_launch(void* const* d_in, const int* in_sizes, int n_in,
                              void* d_out, int out_size, void* d_ws, size_t ws_size,
                              hipStream_t stream) {
  const float* x    = (const float*)d_in[0];
  const float* w    = (const float*)d_in[1];
  const float* bias = (const float*)d_in[2];
  float* out  = (float*)d_out;
  float* part = (float*)d_ws;

  const size_t plane  = (size_t)T_TOK * NE * sizeof(float);        // 4 MB
  const size_t wbytes = (size_t)NE * HID * 2 * sizeof(_Float16);   // 1.44 MB

  int split = (int)((ws_size - wbytes) / plane);
  if (split > 8) split = 8;
  if (split < 1) split = 1;

  _Float16* wc = (_Float16*)((char*)d_ws + (size_t)split * plane);

  convert_w<<<(NE * (HID / 8) + 255) / 256, 256, 0, stream>>>(w, wc);
  logits_mfma<<<(T_TOK / 128) * split, 256, 0, stream>>>(x, wc, part, split);
  topk_kernel<<<T_TOK / 4, 256, 0, stream>>>(part, bias, out, split);
  count_kernel<<<NE, 256, 0, stream>>>(out + (size_t)T_TOK * TOPK,
                                       out + 2 * (size_t)T_TOK * TOPK);
}